// Round 1
// baseline (1344.505 us; speedup 1.0000x reference)
//
#include <hip/hip_runtime.h>
#include <math.h>
#include <float.h>
#include <limits.h>

#define BN      32768   // B*N = 8*4096 query rows
#define D_IN    1024    // input dim
#define E_DIM   128     // codebook dim
#define CB_N    8192    // codebook size

// Workspace layout (floats):
//   proj  : [BN][E_DIM]       at offset 0                (16 MB)
//   ncb_t : [E_DIM][CB_N]     at offset BN*E_DIM         (4 MB, transposed normalized codebook)

// ---------------------------------------------------------------------------
// Kernel 1: normalize codebook rows, store transposed [k][code]
// One wave per code row (4 codes per 256-thread block).
// ---------------------------------------------------------------------------
__global__ __launch_bounds__(256) void normalize_cb_kernel(
    const float* __restrict__ cb, float* __restrict__ ncb_t) {
    const int lane = threadIdx.x & 63;
    const int w    = threadIdx.x >> 6;
    const int code = blockIdx.x * 4 + w;

    const float2 v = *(const float2*)&cb[code * E_DIM + lane * 2];
    float ss = v.x * v.x + v.y * v.y;
#pragma unroll
    for (int m = 1; m < 64; m <<= 1) ss += __shfl_xor(ss, m, 64);
    float norm = sqrtf(ss);
    norm = fmaxf(norm, 1e-12f);
    const float inv = 1.0f / norm;
    ncb_t[(lane * 2 + 0) * CB_N + code] = v.x * inv;
    ncb_t[(lane * 2 + 1) * CB_N + code] = v.y * inv;
}

// ---------------------------------------------------------------------------
// Kernel 2: proj = x @ RP.  M=32768, K=1024, N=128 fp32.
// 64-row tile per block, 256 threads, each thread 4 rows x 8 cols.
// ---------------------------------------------------------------------------
__global__ __launch_bounds__(256) void proj_kernel(
    const float* __restrict__ x, const float* __restrict__ rp,
    float* __restrict__ proj) {
    __shared__ float As[32][68];    // [k][row], pad 68 (16B-aligned rows, breaks write conflicts)
    __shared__ float Bs[32][128];   // [k][col]

    const int tid = threadIdx.x;
    const int tx  = tid & 15;       // col group
    const int ty  = tid >> 4;       // row group
    const int rbase = blockIdx.x * 64;

    float acc[4][8];
#pragma unroll
    for (int i = 0; i < 4; ++i)
#pragma unroll
        for (int j = 0; j < 8; ++j) acc[i][j] = 0.0f;

    for (int kb = 0; kb < D_IN; kb += 32) {
        // Stage A transposed: 64 rows x 32 k
#pragma unroll
        for (int i = 0; i < 2; ++i) {
            const int flat = tid + i * 256;
            const int r  = flat >> 3;
            const int kc = (flat & 7) * 4;
            const float4 a = *(const float4*)&x[(size_t)(rbase + r) * D_IN + kb + kc];
            As[kc + 0][r] = a.x;
            As[kc + 1][r] = a.y;
            As[kc + 2][r] = a.z;
            As[kc + 3][r] = a.w;
        }
        // Stage B directly: 32 k x 128 cols
#pragma unroll
        for (int i = 0; i < 4; ++i) {
            const int flat = tid + i * 256;
            const int kk = flat >> 5;
            const int e4 = (flat & 31) * 4;
            *(float4*)&Bs[kk][e4] = *(const float4*)&rp[(size_t)(kb + kk) * E_DIM + e4];
        }
        __syncthreads();

#pragma unroll
        for (int k = 0; k < 32; ++k) {
            const float4 av = *(const float4*)&As[k][ty * 4];
            const float4 b0 = *(const float4*)&Bs[k][tx * 4];
            const float4 b1 = *(const float4*)&Bs[k][tx * 4 + 64];
            const float a_[4] = {av.x, av.y, av.z, av.w};
            const float b_[8] = {b0.x, b0.y, b0.z, b0.w, b1.x, b1.y, b1.z, b1.w};
#pragma unroll
            for (int qi = 0; qi < 4; ++qi)
#pragma unroll
                for (int ci = 0; ci < 8; ++ci)
                    acc[qi][ci] = fmaf(a_[qi], b_[ci], acc[qi][ci]);
        }
        __syncthreads();
    }

#pragma unroll
    for (int ri = 0; ri < 4; ++ri) {
        const int row = rbase + ty * 4 + ri;
        float4 o0 = {acc[ri][0], acc[ri][1], acc[ri][2], acc[ri][3]};
        float4 o1 = {acc[ri][4], acc[ri][5], acc[ri][6], acc[ri][7]};
        *(float4*)&proj[(size_t)row * E_DIM + tx * 4]      = o0;
        *(float4*)&proj[(size_t)row * E_DIM + 64 + tx * 4] = o1;
    }
}

// ---------------------------------------------------------------------------
// Kernel 3: fused scores + argmax.
// Block: 64 queries, stream all 8192 codes in 64-code chunks.
// 256 threads as 16(tx: code groups of 4) x 4(ty: query groups of 4 -- wait,
// ty in 0..15 query groups of 4). Each thread: acc[4 queries][4 codes].
// Tie-break: smallest code index (matches jnp.argmin over axis 0).
// ---------------------------------------------------------------------------
__global__ __launch_bounds__(256) void argmax_kernel(
    const float* __restrict__ proj, const float* __restrict__ ncb_t,
    int* __restrict__ out) {
    __shared__ float Qs[128][68];   // [k][query], padded for 16B alignment
    __shared__ float Cs[128][64];   // [k][code-in-chunk]
    __shared__ float redS[64][16];
    __shared__ int   redI[64][16];

    const int tid = threadIdx.x;
    const int tx  = tid & 15;       // code group (4 codes)
    const int ty  = tid >> 4;       // query group (4 queries)
    const int qbase = blockIdx.x * 64;

    // Stage queries once, transposed.
#pragma unroll
    for (int i = 0; i < 8; ++i) {
        const int flat = tid + i * 256;
        const int q  = flat >> 5;
        const int k4 = (flat & 31) * 4;
        const float4 v = *(const float4*)&proj[(size_t)(qbase + q) * E_DIM + k4];
        Qs[k4 + 0][q] = v.x;
        Qs[k4 + 1][q] = v.y;
        Qs[k4 + 2][q] = v.z;
        Qs[k4 + 3][q] = v.w;
    }

    float bestS[4] = {-FLT_MAX, -FLT_MAX, -FLT_MAX, -FLT_MAX};
    int   bestI[4] = {0, 0, 0, 0};

    for (int c0 = 0; c0 < CB_N; c0 += 64) {
        __syncthreads();   // covers first-iter query staging AND prior compute
        // Stage 64-code chunk from transposed normalized codebook.
#pragma unroll
        for (int i = 0; i < 8; ++i) {
            const int flat = tid + i * 256;
            const int k  = flat >> 4;
            const int cg = (flat & 15) * 4;
            *(float4*)&Cs[k][cg] = *(const float4*)&ncb_t[(size_t)k * CB_N + c0 + cg];
        }
        __syncthreads();

        float acc[4][4];
#pragma unroll
        for (int qi = 0; qi < 4; ++qi)
#pragma unroll
            for (int ci = 0; ci < 4; ++ci) acc[qi][ci] = 0.0f;

#pragma unroll 4
        for (int k = 0; k < 128; ++k) {
            const float4 qv = *(const float4*)&Qs[k][ty * 4];
            const float4 cv = *(const float4*)&Cs[k][tx * 4];
            const float q_[4] = {qv.x, qv.y, qv.z, qv.w};
            const float c_[4] = {cv.x, cv.y, cv.z, cv.w};
#pragma unroll
            for (int qi = 0; qi < 4; ++qi)
#pragma unroll
                for (int ci = 0; ci < 4; ++ci)
                    acc[qi][ci] = fmaf(q_[qi], c_[ci], acc[qi][ci]);
        }

        // Update per-thread best (codes ascending; strict > keeps smallest idx)
#pragma unroll
        for (int qi = 0; qi < 4; ++qi) {
#pragma unroll
            for (int ci = 0; ci < 4; ++ci) {
                const int idx = c0 + tx * 4 + ci;
                if (acc[qi][ci] > bestS[qi]) {
                    bestS[qi] = acc[qi][ci];
                    bestI[qi] = idx;
                }
            }
        }
    }

    // Cross-thread reduction: 16 tx candidates per query.
#pragma unroll
    for (int qi = 0; qi < 4; ++qi) {
        redS[ty * 4 + qi][tx] = bestS[qi];
        redI[ty * 4 + qi][tx] = bestI[qi];
    }
    __syncthreads();

    if (tid < 64) {
        const int q = tid;
        float bs = -FLT_MAX;
        int   bi = INT_MAX;
#pragma unroll
        for (int t = 0; t < 16; ++t) {
            const float s = redS[q][t];
            const int   i = redI[q][t];
            if (s > bs || (s == bs && i < bi)) { bs = s; bi = i; }
        }
        out[qbase + q] = bi;
    }
}

// ---------------------------------------------------------------------------
extern "C" void kernel_launch(void* const* d_in, const int* in_sizes, int n_in,
                              void* d_out, int out_size, void* d_ws, size_t ws_size,
                              hipStream_t stream) {
    const float* x  = (const float*)d_in[0];   // [8,4096,1024]
    const float* rp = (const float*)d_in[1];   // [1024,128]
    const float* cb = (const float*)d_in[2];   // [8192,128]
    int* out = (int*)d_out;                    // [8,4096] int32

    float* proj  = (float*)d_ws;               // [BN][128]
    float* ncb_t = proj + (size_t)BN * E_DIM;  // [128][8192]

    normalize_cb_kernel<<<CB_N / 4, 256, 0, stream>>>(cb, ncb_t);
    proj_kernel<<<BN / 64, 256, 0, stream>>>(x, rp, proj);
    argmax_kernel<<<BN / 64, 256, 0, stream>>>(proj, ncb_t, out);
}

// Round 2
// 464.974 us; speedup vs baseline: 2.8916x; 2.8916x over previous
//
#include <hip/hip_runtime.h>
#include <math.h>
#include <float.h>
#include <limits.h>

#define BN      32768   // B*N query rows
#define D_IN    1024
#define E_DIM   128
#define CB_N    8192

typedef _Float16 f16x8 __attribute__((ext_vector_type(8)));
typedef _Float16 f16x4 __attribute__((ext_vector_type(4)));
typedef float    f32x4 __attribute__((ext_vector_type(4)));

// Workspace (bytes):
//   qh : [BN][128] f16   8 MB   (proj*16 hi)
//   ql : [BN][128] f16   8 MB   (proj*16 lo)
//   ph : [CB_N/16][4][64][8] f16  2 MB (ncb*256 hi, B-fragment packed)
//   pl : same                      2 MB
// Total 20 MB (same footprint as round 1).

// ---------------------------------------------------------------------------
// Kernel 1: normalize codebook (scale 256) and pack into MFMA B-fragment
// order for 16x16x32: value at pack[((g*4+kb)*64 + quad*16 + col)*8 + j]
//   = ncb[g*16 + col][kb*32 + quad*8 + j] * 256
// One 16-code tile (g) per 256-thread block.
// ---------------------------------------------------------------------------
__global__ __launch_bounds__(256) void pack_cb_kernel(
    const float* __restrict__ cb, _Float16* __restrict__ ph,
    _Float16* __restrict__ pl) {
    __shared__ float L[16][129];   // padded: breaks 16-way bank conflict in pack phase
    const int t = threadIdx.x;
    const int g = blockIdx.x;

    // --- norm phase: code c = t>>4, part p = t&15 (8 elems each) ---
    const int c = t >> 4, p = t & 15;
    const float4 v0 = *(const float4*)&cb[(size_t)(g * 16 + c) * E_DIM + p * 8];
    const float4 v1 = *(const float4*)&cb[(size_t)(g * 16 + c) * E_DIM + p * 8 + 4];
    float ss = v0.x * v0.x + v0.y * v0.y + v0.z * v0.z + v0.w * v0.w
             + v1.x * v1.x + v1.y * v1.y + v1.z * v1.z + v1.w * v1.w;
#pragma unroll
    for (int m = 1; m < 16; m <<= 1) ss += __shfl_xor(ss, m);
    const float inv = 256.0f / fmaxf(sqrtf(ss), 1e-12f);

    L[c][p * 8 + 0] = v0.x * inv; L[c][p * 8 + 1] = v0.y * inv;
    L[c][p * 8 + 2] = v0.z * inv; L[c][p * 8 + 3] = v0.w * inv;
    L[c][p * 8 + 4] = v1.x * inv; L[c][p * 8 + 5] = v1.y * inv;
    L[c][p * 8 + 6] = v1.z * inv; L[c][p * 8 + 7] = v1.w * inv;
    __syncthreads();

    // --- pack phase: thread t -> (kb, lane) writes 8 f16 hi + 8 f16 lo ---
    const int kb = t >> 6, lane = t & 63;
    const int quad = (lane >> 4), col = lane & 15;
    f16x8 h, l;
#pragma unroll
    for (int j = 0; j < 8; ++j) {
        const float v = L[col][kb * 32 + quad * 8 + j];
        const _Float16 hv = (_Float16)v;
        h[j] = hv;
        l[j] = (_Float16)(v - (float)hv);
    }
    const size_t off = ((size_t)(g * 4 + kb) * 64 + lane) * 8;
    *(f16x8*)&ph[off] = h;
    *(f16x8*)&pl[off] = l;
}

// ---------------------------------------------------------------------------
// Kernel 2: proj = x @ RP (fp32), epilogue splits proj*16 into f16 hi/lo.
// ---------------------------------------------------------------------------
__global__ __launch_bounds__(256) void proj_kernel(
    const float* __restrict__ x, const float* __restrict__ rp,
    _Float16* __restrict__ qh, _Float16* __restrict__ ql) {
    __shared__ float As[32][68];
    __shared__ float Bs[32][128];

    const int tid = threadIdx.x;
    const int tx  = tid & 15;
    const int ty  = tid >> 4;
    const int rbase = blockIdx.x * 64;

    float acc[4][8];
#pragma unroll
    for (int i = 0; i < 4; ++i)
#pragma unroll
        for (int j = 0; j < 8; ++j) acc[i][j] = 0.0f;

    for (int kb = 0; kb < D_IN; kb += 32) {
#pragma unroll
        for (int i = 0; i < 2; ++i) {
            const int flat = tid + i * 256;
            const int r  = flat >> 3;
            const int kc = (flat & 7) * 4;
            const float4 a = *(const float4*)&x[(size_t)(rbase + r) * D_IN + kb + kc];
            As[kc + 0][r] = a.x;
            As[kc + 1][r] = a.y;
            As[kc + 2][r] = a.z;
            As[kc + 3][r] = a.w;
        }
#pragma unroll
        for (int i = 0; i < 4; ++i) {
            const int flat = tid + i * 256;
            const int kk = flat >> 5;
            const int e4 = (flat & 31) * 4;
            *(float4*)&Bs[kk][e4] = *(const float4*)&rp[(size_t)(kb + kk) * E_DIM + e4];
        }
        __syncthreads();

#pragma unroll
        for (int k = 0; k < 32; ++k) {
            const float4 av = *(const float4*)&As[k][ty * 4];
            const float4 b0 = *(const float4*)&Bs[k][tx * 4];
            const float4 b1 = *(const float4*)&Bs[k][tx * 4 + 64];
            const float a_[4] = {av.x, av.y, av.z, av.w};
            const float b_[8] = {b0.x, b0.y, b0.z, b0.w, b1.x, b1.y, b1.z, b1.w};
#pragma unroll
            for (int qi = 0; qi < 4; ++qi)
#pragma unroll
                for (int ci = 0; ci < 8; ++ci)
                    acc[qi][ci] = fmaf(a_[qi], b_[ci], acc[qi][ci]);
        }
        __syncthreads();
    }

#pragma unroll
    for (int ri = 0; ri < 4; ++ri) {
        const int row = rbase + ty * 4 + ri;
        _Float16 h[8], l[8];
#pragma unroll
        for (int j = 0; j < 8; ++j) {
            const float v = acc[ri][j] * 16.0f;   // exact pow2 scale: keeps lo out of denormals
            const _Float16 hv = (_Float16)v;
            h[j] = hv;
            l[j] = (_Float16)(v - (float)hv);
        }
        f16x4 h0 = {h[0], h[1], h[2], h[3]}, h1 = {h[4], h[5], h[6], h[7]};
        f16x4 l0 = {l[0], l[1], l[2], l[3]}, l1 = {l[4], l[5], l[6], l[7]};
        *(f16x4*)&qh[(size_t)row * E_DIM + tx * 4]      = h0;
        *(f16x4*)&qh[(size_t)row * E_DIM + 64 + tx * 4] = h1;
        *(f16x4*)&ql[(size_t)row * E_DIM + tx * 4]      = l0;
        *(f16x4*)&ql[(size_t)row * E_DIM + 64 + tx * 4] = l1;
    }
}

// ---------------------------------------------------------------------------
// Kernel 3: f16-split MFMA scores + fused argmax.
// Block = 4 waves x 64 threads; all waves share 64 queries (A frags held in
// VGPRs), each wave scans a disjoint quarter of the codes. No LDS / no
// barriers in the hot loop; final 4-way merge via tiny LDS.
// ---------------------------------------------------------------------------
__global__ __launch_bounds__(256, 2) void scores_kernel(
    const _Float16* __restrict__ qh, const _Float16* __restrict__ ql,
    const _Float16* __restrict__ ph, const _Float16* __restrict__ pl,
    int* __restrict__ out) {
    __shared__ float ls[4][64];
    __shared__ int   li[4][64];

    const int tid  = threadIdx.x;
    const int w    = tid >> 6;
    const int lane = tid & 63;
    const int quad = lane >> 4, col = lane & 15;
    const int qb   = blockIdx.x * 64;

    // A fragments (persistent): A[m=lane&15][k=quad*8+j], 4 m-tiles x 4 k-blocks
    f16x8 ah[4][4], al[4][4];
#pragma unroll
    for (int mt = 0; mt < 4; ++mt)
#pragma unroll
        for (int kb = 0; kb < 4; ++kb) {
            const size_t off = (size_t)(qb + mt * 16 + col) * E_DIM + kb * 32 + quad * 8;
            ah[mt][kb] = *(const f16x8*)&qh[off];
            al[mt][kb] = *(const f16x8*)&ql[off];
        }

    float bs[16];
    int   bi[16];
#pragma unroll
    for (int s = 0; s < 16; ++s) { bs[s] = -FLT_MAX; bi[s] = 0; }

    const int g0 = w * (CB_N / 16 / 4);   // 128 16-code tiles per wave
    for (int t = 0; t < CB_N / 16 / 4; ++t) {
        const int g = g0 + t;
        f16x8 bh[4], bl[4];
#pragma unroll
        for (int kb = 0; kb < 4; ++kb) {
            const size_t off = ((size_t)(g * 4 + kb) * 64 + lane) * 8;
            bh[kb] = *(const f16x8*)&ph[off];
            bl[kb] = *(const f16x8*)&pl[off];
        }

        f32x4 acc[4];
#pragma unroll
        for (int mt = 0; mt < 4; ++mt) acc[mt] = (f32x4){0.f, 0.f, 0.f, 0.f};

        // hi*hi
#pragma unroll
        for (int kb = 0; kb < 4; ++kb)
#pragma unroll
            for (int mt = 0; mt < 4; ++mt)
                acc[mt] = __builtin_amdgcn_mfma_f32_16x16x32_f16(ah[mt][kb], bh[kb], acc[mt], 0, 0, 0);
        // hi*lo
#pragma unroll
        for (int kb = 0; kb < 4; ++kb)
#pragma unroll
            for (int mt = 0; mt < 4; ++mt)
                acc[mt] = __builtin_amdgcn_mfma_f32_16x16x32_f16(ah[mt][kb], bl[kb], acc[mt], 0, 0, 0);
        // lo*hi
#pragma unroll
        for (int kb = 0; kb < 4; ++kb)
#pragma unroll
            for (int mt = 0; mt < 4; ++mt)
                acc[mt] = __builtin_amdgcn_mfma_f32_16x16x32_f16(al[mt][kb], bh[kb], acc[mt], 0, 0, 0);

        // C/D layout: col(lane&15)=code-in-tile, row(quad*4+r)=query row.
        // All 16 C values of this lane share ONE candidate code.
        const int code = g * 16 + col;
#pragma unroll
        for (int mt = 0; mt < 4; ++mt)
#pragma unroll
            for (int r = 0; r < 4; ++r) {
                const float v = acc[mt][r];
                const int s = mt * 4 + r;
                if (v > bs[s]) { bs[s] = v; bi[s] = code; }  // codes ascending: strict > keeps min idx
            }
    }

    // Reduce the 16 code-columns (lanes within a quad group) per query.
#pragma unroll
    for (int s = 0; s < 16; ++s) {
#pragma unroll
        for (int m = 1; m < 16; m <<= 1) {
            const float os = __shfl_xor(bs[s], m);
            const int   oi = __shfl_xor(bi[s], m);
            if (os > bs[s] || (os == bs[s] && oi < bi[s])) { bs[s] = os; bi[s] = oi; }
        }
    }

    if (col == 0) {
#pragma unroll
        for (int mt = 0; mt < 4; ++mt)
#pragma unroll
            for (int r = 0; r < 4; ++r) {
                ls[w][mt * 16 + quad * 4 + r] = bs[mt * 4 + r];
                li[w][mt * 16 + quad * 4 + r] = bi[mt * 4 + r];
            }
    }
    __syncthreads();

    // 4-way merge across waves (ascending code ranges: strict > keeps min idx)
    if (tid < 64) {
        float s = ls[0][tid];
        int   i = li[0][tid];
#pragma unroll
        for (int ww = 1; ww < 4; ++ww) {
            const float os = ls[ww][tid];
            const int   oi = li[ww][tid];
            if (os > s) { s = os; i = oi; }
        }
        out[qb + tid] = i;
    }
}

// ---------------------------------------------------------------------------
extern "C" void kernel_launch(void* const* d_in, const int* in_sizes, int n_in,
                              void* d_out, int out_size, void* d_ws, size_t ws_size,
                              hipStream_t stream) {
    const float* x  = (const float*)d_in[0];   // [8,4096,1024]
    const float* rp = (const float*)d_in[1];   // [1024,128]
    const float* cb = (const float*)d_in[2];   // [8192,128]
    int* out = (int*)d_out;                    // [8,4096] int32

    _Float16* qh = (_Float16*)d_ws;                          // 8 MB
    _Float16* ql = qh + (size_t)BN * E_DIM;                  // 8 MB
    _Float16* ph = ql + (size_t)BN * E_DIM;                  // 2 MB
    _Float16* pl = ph + (size_t)CB_N * E_DIM;                // 2 MB

    pack_cb_kernel<<<CB_N / 16, 256, 0, stream>>>(cb, ph, pl);
    proj_kernel<<<BN / 64, 256, 0, stream>>>(x, rp, qh, ql);
    scores_kernel<<<BN / 64, 256, 0, stream>>>(qh, ql, ph, pl, out);
}

// Round 3
// 419.366 us; speedup vs baseline: 3.2060x; 1.1088x over previous
//
#include <hip/hip_runtime.h>
#include <math.h>
#include <float.h>
#include <limits.h>

#define BN      32768   // B*N query rows
#define D_IN    1024
#define E_DIM   128
#define CB_N    8192

typedef _Float16 f16x8 __attribute__((ext_vector_type(8)));
typedef _Float16 f16x4 __attribute__((ext_vector_type(4)));
typedef float    f32x4 __attribute__((ext_vector_type(4)));

// Workspace:
//   qh  : [BN][128] f16                 8   MB  (proj*16 hi)
//   ql  : [BN][128] f16                 8   MB  (proj*16 lo)
//   ph  : [CB_N/16][4][64][8] f16       2   MB  (ncb*256 hi, B-frag packed)
//   pl  : same                          2   MB
//   rph : [32*8][64][8] f16             0.25 MB (rp*64 hi, B-frag packed)
//   rpl : same                          0.25 MB
// Total 20.5 MB.

// ---------------------------------------------------------------------------
// Kernel 1: normalize codebook (scale 256), pack into MFMA B-frag order.
// (unchanged from round 2 — validated)
// ---------------------------------------------------------------------------
__global__ __launch_bounds__(256) void pack_cb_kernel(
    const float* __restrict__ cb, _Float16* __restrict__ ph,
    _Float16* __restrict__ pl) {
    __shared__ float L[16][129];
    const int t = threadIdx.x;
    const int g = blockIdx.x;

    const int c = t >> 4, p = t & 15;
    const float4 v0 = *(const float4*)&cb[(size_t)(g * 16 + c) * E_DIM + p * 8];
    const float4 v1 = *(const float4*)&cb[(size_t)(g * 16 + c) * E_DIM + p * 8 + 4];
    float ss = v0.x * v0.x + v0.y * v0.y + v0.z * v0.z + v0.w * v0.w
             + v1.x * v1.x + v1.y * v1.y + v1.z * v1.z + v1.w * v1.w;
#pragma unroll
    for (int m = 1; m < 16; m <<= 1) ss += __shfl_xor(ss, m);
    const float inv = 256.0f / fmaxf(sqrtf(ss), 1e-12f);

    L[c][p * 8 + 0] = v0.x * inv; L[c][p * 8 + 1] = v0.y * inv;
    L[c][p * 8 + 2] = v0.z * inv; L[c][p * 8 + 3] = v0.w * inv;
    L[c][p * 8 + 4] = v1.x * inv; L[c][p * 8 + 5] = v1.y * inv;
    L[c][p * 8 + 6] = v1.z * inv; L[c][p * 8 + 7] = v1.w * inv;
    __syncthreads();

    const int kb = t >> 6, lane = t & 63;
    const int quad = (lane >> 4), col = lane & 15;
    f16x8 h, l;
#pragma unroll
    for (int j = 0; j < 8; ++j) {
        const float v = L[col][kb * 32 + quad * 8 + j];
        const _Float16 hv = (_Float16)v;
        h[j] = hv;
        l[j] = (_Float16)(v - (float)hv);
    }
    const size_t off = ((size_t)(g * 4 + kb) * 64 + lane) * 8;
    *(f16x8*)&ph[off] = h;
    *(f16x8*)&pl[off] = l;
}

// ---------------------------------------------------------------------------
// Kernel 1b: pack rp*64 split hi/lo into B-frag order.
// Block b = kb*8 + nt (kb: 32-k chunk, nt: 16-col tile). 64 threads = 1 wave.
// B[n=lane&15][k=quad*8+j] at [((kb*8+nt)*64 + lane)*8 + j].
// ---------------------------------------------------------------------------
__global__ __launch_bounds__(64) void pack_rp_kernel(
    const float* __restrict__ rp, _Float16* __restrict__ rph,
    _Float16* __restrict__ rpl) {
    const int b = blockIdx.x;
    const int kb = b >> 3, nt = b & 7;
    const int lane = threadIdx.x;
    const int quad = lane >> 4, col = lane & 15;
    f16x8 h, l;
#pragma unroll
    for (int j = 0; j < 8; ++j) {
        const float v = rp[(size_t)(kb * 32 + quad * 8 + j) * E_DIM + nt * 16 + col] * 64.0f;
        const _Float16 hv = (_Float16)v;
        h[j] = hv;
        l[j] = (_Float16)(v - (float)hv);
    }
    const size_t off = ((size_t)b * 64 + lane) * 8;
    *(f16x8*)&rph[off] = h;
    *(f16x8*)&rpl[off] = l;
}

// ---------------------------------------------------------------------------
// Kernel 2: proj = x @ RP via f16-split MFMA (3 passes, lo*lo dropped).
// x scaled by 512, rp by 64 -> acc = 32768*proj; epilogue stores proj*16
// hi/lo (divide by 2048, exact). Block: 64 rows, all 128 cols, K streamed in
// 32-chunks. Wave w owns cols [w*32, w*32+32). x staged fp32->f16 hi/lo in
// LDS (A-frag readable, row stride 40 halfwords: 2-way banks, 16B aligned).
// HBM-bound: x read once = 128 MB.
// ---------------------------------------------------------------------------
#define PAD_ROW 40   // halfwords per 32-k row (32 data + 8 pad)

__global__ __launch_bounds__(256) void proj_kernel(
    const float* __restrict__ x,
    const _Float16* __restrict__ rph, const _Float16* __restrict__ rpl,
    _Float16* __restrict__ qh, _Float16* __restrict__ ql) {
    __shared__ _Float16 Ah[64 * PAD_ROW];
    __shared__ _Float16 Al[64 * PAD_ROW];

    const int tid  = threadIdx.x;
    const int lane = tid & 63;
    const int w    = tid >> 6;
    const int quad = lane >> 4, col = lane & 15;
    const int rbase = blockIdx.x * 64;

    // staging: thread covers x[srow + 32*i][skc..skc+3], i=0,1
    const int srow = tid >> 3;        // 0..31
    const int skc  = (tid & 7) * 4;   // 0,4,..,28

    f32x4 acc[4][2];
#pragma unroll
    for (int mt = 0; mt < 4; ++mt)
#pragma unroll
        for (int h = 0; h < 2; ++h) acc[mt][h] = (f32x4){0.f, 0.f, 0.f, 0.f};

    float4 pre[2];
#pragma unroll
    for (int i = 0; i < 2; ++i)
        pre[i] = *(const float4*)&x[(size_t)(rbase + srow + 32 * i) * D_IN + skc];

    for (int kb = 0; kb < 32; ++kb) {
        // convert + write staged tile
#pragma unroll
        for (int i = 0; i < 2; ++i) {
            const float vv[4] = {pre[i].x, pre[i].y, pre[i].z, pre[i].w};
            f16x4 h4, l4;
#pragma unroll
            for (int j = 0; j < 4; ++j) {
                const float v = vv[j] * 512.0f;
                const _Float16 hv = (_Float16)v;
                h4[j] = hv;
                l4[j] = (_Float16)(v - (float)hv);
            }
            const int base = (srow + 32 * i) * PAD_ROW + skc;
            *(f16x4*)&Ah[base] = h4;
            *(f16x4*)&Al[base] = l4;
        }
        __syncthreads();

        // prefetch next k-chunk (independent of LDS)
        if (kb + 1 < 32) {
#pragma unroll
            for (int i = 0; i < 2; ++i)
                pre[i] = *(const float4*)&x[(size_t)(rbase + srow + 32 * i) * D_IN + (kb + 1) * 32 + skc];
        }

        // B frags for this wave's two 16-col tiles
        f16x8 bh[2], bl[2];
#pragma unroll
        for (int h = 0; h < 2; ++h) {
            const int nt = w * 2 + h;
            const size_t off = ((size_t)(kb * 8 + nt) * 64 + lane) * 8;
            bh[h] = *(const f16x8*)&rph[off];
            bl[h] = *(const f16x8*)&rpl[off];
        }

        // A frags from LDS
        f16x8 ah[4], al[4];
#pragma unroll
        for (int mt = 0; mt < 4; ++mt) {
            const int base = (mt * 16 + col) * PAD_ROW + quad * 8;
            ah[mt] = *(const f16x8*)&Ah[base];
            al[mt] = *(const f16x8*)&Al[base];
        }

#pragma unroll
        for (int mt = 0; mt < 4; ++mt)
#pragma unroll
            for (int h = 0; h < 2; ++h)
                acc[mt][h] = __builtin_amdgcn_mfma_f32_16x16x32_f16(ah[mt], bh[h], acc[mt][h], 0, 0, 0);
#pragma unroll
        for (int mt = 0; mt < 4; ++mt)
#pragma unroll
            for (int h = 0; h < 2; ++h)
                acc[mt][h] = __builtin_amdgcn_mfma_f32_16x16x32_f16(ah[mt], bl[h], acc[mt][h], 0, 0, 0);
#pragma unroll
        for (int mt = 0; mt < 4; ++mt)
#pragma unroll
            for (int h = 0; h < 2; ++h)
                acc[mt][h] = __builtin_amdgcn_mfma_f32_16x16x32_f16(al[mt], bh[h], acc[mt][h], 0, 0, 0);

        __syncthreads();
    }

    // epilogue: C/D layout col=lane&15, row=quad*4+r
#pragma unroll
    for (int mt = 0; mt < 4; ++mt) {
#pragma unroll
        for (int h = 0; h < 2; ++h) {
#pragma unroll
            for (int r = 0; r < 4; ++r) {
                const float v = acc[mt][h][r] * (1.0f / 2048.0f);  // *16/32768 exact
                const _Float16 hv = (_Float16)v;
                const _Float16 lv = (_Float16)(v - (float)hv);
                const size_t o = (size_t)(rbase + mt * 16 + quad * 4 + r) * E_DIM
                               + w * 32 + h * 16 + col;
                qh[o] = hv;
                ql[o] = lv;
            }
        }
    }
}

// ---------------------------------------------------------------------------
// Kernel 3: f16-split MFMA scores + fused argmax (unchanged from round 2).
// ---------------------------------------------------------------------------
__global__ __launch_bounds__(256, 2) void scores_kernel(
    const _Float16* __restrict__ qh, const _Float16* __restrict__ ql,
    const _Float16* __restrict__ ph, const _Float16* __restrict__ pl,
    int* __restrict__ out) {
    __shared__ float ls[4][64];
    __shared__ int   li[4][64];

    const int tid  = threadIdx.x;
    const int w    = tid >> 6;
    const int lane = tid & 63;
    const int quad = lane >> 4, col = lane & 15;
    const int qb   = blockIdx.x * 64;

    f16x8 ah[4][4], al[4][4];
#pragma unroll
    for (int mt = 0; mt < 4; ++mt)
#pragma unroll
        for (int kb = 0; kb < 4; ++kb) {
            const size_t off = (size_t)(qb + mt * 16 + col) * E_DIM + kb * 32 + quad * 8;
            ah[mt][kb] = *(const f16x8*)&qh[off];
            al[mt][kb] = *(const f16x8*)&ql[off];
        }

    float bs[16];
    int   bi[16];
#pragma unroll
    for (int s = 0; s < 16; ++s) { bs[s] = -FLT_MAX; bi[s] = 0; }

    const int g0 = w * (CB_N / 16 / 4);
    for (int t = 0; t < CB_N / 16 / 4; ++t) {
        const int g = g0 + t;
        f16x8 bh[4], bl[4];
#pragma unroll
        for (int kb = 0; kb < 4; ++kb) {
            const size_t off = ((size_t)(g * 4 + kb) * 64 + lane) * 8;
            bh[kb] = *(const f16x8*)&ph[off];
            bl[kb] = *(const f16x8*)&pl[off];
        }

        f32x4 acc[4];
#pragma unroll
        for (int mt = 0; mt < 4; ++mt) acc[mt] = (f32x4){0.f, 0.f, 0.f, 0.f};

#pragma unroll
        for (int kb = 0; kb < 4; ++kb)
#pragma unroll
            for (int mt = 0; mt < 4; ++mt)
                acc[mt] = __builtin_amdgcn_mfma_f32_16x16x32_f16(ah[mt][kb], bh[kb], acc[mt], 0, 0, 0);
#pragma unroll
        for (int kb = 0; kb < 4; ++kb)
#pragma unroll
            for (int mt = 0; mt < 4; ++mt)
                acc[mt] = __builtin_amdgcn_mfma_f32_16x16x32_f16(ah[mt][kb], bl[kb], acc[mt], 0, 0, 0);
#pragma unroll
        for (int kb = 0; kb < 4; ++kb)
#pragma unroll
            for (int mt = 0; mt < 4; ++mt)
                acc[mt] = __builtin_amdgcn_mfma_f32_16x16x32_f16(al[mt][kb], bh[kb], acc[mt], 0, 0, 0);

        const int code = g * 16 + col;
#pragma unroll
        for (int mt = 0; mt < 4; ++mt)
#pragma unroll
            for (int r = 0; r < 4; ++r) {
                const float v = acc[mt][r];
                const int s = mt * 4 + r;
                if (v > bs[s]) { bs[s] = v; bi[s] = code; }
            }
    }

#pragma unroll
    for (int s = 0; s < 16; ++s) {
#pragma unroll
        for (int m = 1; m < 16; m <<= 1) {
            const float os = __shfl_xor(bs[s], m);
            const int   oi = __shfl_xor(bi[s], m);
            if (os > bs[s] || (os == bs[s] && oi < bi[s])) { bs[s] = os; bi[s] = oi; }
        }
    }

    if (col == 0) {
#pragma unroll
        for (int mt = 0; mt < 4; ++mt)
#pragma unroll
            for (int r = 0; r < 4; ++r) {
                ls[w][mt * 16 + quad * 4 + r] = bs[mt * 4 + r];
                li[w][mt * 16 + quad * 4 + r] = bi[mt * 4 + r];
            }
    }
    __syncthreads();

    if (tid < 64) {
        float s = ls[0][tid];
        int   i = li[0][tid];
#pragma unroll
        for (int ww = 1; ww < 4; ++ww) {
            const float os = ls[ww][tid];
            if (os > s) { s = os; i = li[ww][tid]; }
        }
        out[qb + tid] = i;
    }
}

// ---------------------------------------------------------------------------
extern "C" void kernel_launch(void* const* d_in, const int* in_sizes, int n_in,
                              void* d_out, int out_size, void* d_ws, size_t ws_size,
                              hipStream_t stream) {
    const float* x  = (const float*)d_in[0];   // [8,4096,1024]
    const float* rp = (const float*)d_in[1];   // [1024,128]
    const float* cb = (const float*)d_in[2];   // [8192,128]
    int* out = (int*)d_out;                    // [8,4096] int32

    _Float16* qh  = (_Float16*)d_ws;                         // 8 MB
    _Float16* ql  = qh  + (size_t)BN * E_DIM;                // 8 MB
    _Float16* ph  = ql  + (size_t)BN * E_DIM;                // 2 MB
    _Float16* pl  = ph  + (size_t)CB_N * E_DIM;              // 2 MB
    _Float16* rph = pl  + (size_t)CB_N * E_DIM;              // 256 KB
    _Float16* rpl = rph + (size_t)D_IN * E_DIM;              // 256 KB

    pack_cb_kernel<<<CB_N / 16, 256, 0, stream>>>(cb, ph, pl);
    pack_rp_kernel<<<256, 64, 0, stream>>>(rp, rph, rpl);
    proj_kernel<<<BN / 64, 256, 0, stream>>>(x, rph, rpl, qh, ql);
    scores_kernel<<<BN / 64, 256, 0, stream>>>(qh, ql, ph, pl, out);
}

// Round 4
// 395.609 us; speedup vs baseline: 3.3986x; 1.0601x over previous
//
#include <hip/hip_runtime.h>
#include <math.h>
#include <float.h>
#include <limits.h>

#define BN      32768   // B*N query rows
#define D_IN    1024
#define E_DIM   128
#define CB_N    8192

typedef _Float16 f16x8 __attribute__((ext_vector_type(8)));
typedef _Float16 f16x4 __attribute__((ext_vector_type(4)));
typedef float    f32x4 __attribute__((ext_vector_type(4)));

// Workspace:
//   ph  : [CB_N/16][4][64][8] f16   2 MB  (ncb*256 hi, B-frag packed)
//   pl  : same                      2 MB
//   rph : [32*8][64][8] f16         0.25 MB (rp*64 hi, B-frag packed)
//   rpl : same                      0.25 MB

// ---------------------------------------------------------------------------
// Kernel 1: normalize codebook (scale 256), pack into MFMA B-frag order.
// (validated rounds 2-3)
// ---------------------------------------------------------------------------
__global__ __launch_bounds__(256) void pack_cb_kernel(
    const float* __restrict__ cb, _Float16* __restrict__ ph,
    _Float16* __restrict__ pl) {
    __shared__ float L[16][129];
    const int t = threadIdx.x;
    const int g = blockIdx.x;

    const int c = t >> 4, p = t & 15;
    const float4 v0 = *(const float4*)&cb[(size_t)(g * 16 + c) * E_DIM + p * 8];
    const float4 v1 = *(const float4*)&cb[(size_t)(g * 16 + c) * E_DIM + p * 8 + 4];
    float ss = v0.x * v0.x + v0.y * v0.y + v0.z * v0.z + v0.w * v0.w
             + v1.x * v1.x + v1.y * v1.y + v1.z * v1.z + v1.w * v1.w;
#pragma unroll
    for (int m = 1; m < 16; m <<= 1) ss += __shfl_xor(ss, m);
    const float inv = 256.0f / fmaxf(sqrtf(ss), 1e-12f);

    L[c][p * 8 + 0] = v0.x * inv; L[c][p * 8 + 1] = v0.y * inv;
    L[c][p * 8 + 2] = v0.z * inv; L[c][p * 8 + 3] = v0.w * inv;
    L[c][p * 8 + 4] = v1.x * inv; L[c][p * 8 + 5] = v1.y * inv;
    L[c][p * 8 + 6] = v1.z * inv; L[c][p * 8 + 7] = v1.w * inv;
    __syncthreads();

    const int kb = t >> 6, lane = t & 63;
    const int quad = (lane >> 4), col = lane & 15;
    f16x8 h, l;
#pragma unroll
    for (int j = 0; j < 8; ++j) {
        const float v = L[col][kb * 32 + quad * 8 + j];
        const _Float16 hv = (_Float16)v;
        h[j] = hv;
        l[j] = (_Float16)(v - (float)hv);
    }
    const size_t off = ((size_t)(g * 4 + kb) * 64 + lane) * 8;
    *(f16x8*)&ph[off] = h;
    *(f16x8*)&pl[off] = l;
}

// ---------------------------------------------------------------------------
// Kernel 1b: pack rp*64 split hi/lo into B-frag order. (validated round 3)
// ---------------------------------------------------------------------------
__global__ __launch_bounds__(64) void pack_rp_kernel(
    const float* __restrict__ rp, _Float16* __restrict__ rph,
    _Float16* __restrict__ rpl) {
    const int b = blockIdx.x;
    const int kb = b >> 3, nt = b & 7;
    const int lane = threadIdx.x;
    const int quad = lane >> 4, col = lane & 15;
    f16x8 h, l;
#pragma unroll
    for (int j = 0; j < 8; ++j) {
        const float v = rp[(size_t)(kb * 32 + quad * 8 + j) * E_DIM + nt * 16 + col] * 64.0f;
        const _Float16 hv = (_Float16)v;
        h[j] = hv;
        l[j] = (_Float16)(v - (float)hv);
    }
    const size_t off = ((size_t)b * 64 + lane) * 8;
    *(f16x8*)&rph[off] = h;
    *(f16x8*)&rpl[off] = l;
}

// ---------------------------------------------------------------------------
// Kernel 2: FUSED proj + scores + argmax.
// Phase 1: proj for 64 queries (round-3 proj loop) -> LDS [query][k] f32.
// Phase 2: A-frags (hi/lo f16) from LDS; wave w = (wq = w>>1 query half of
// 32, wc = w&1 code half of 4096). B-frags register double-buffered
// (prefetch tile t+1 during tile t's 36 MFMAs). Per-lane argmax, shuffle
// reduce, 2-way cross-half merge in LDS.
// ---------------------------------------------------------------------------
#define PAD_ROW 40    // phase-1 staging row stride (halfwords)
#define PPITCH  132   // phase-2 proj buffer row pitch (dwords), 528 B 16B-aligned

__global__ __launch_bounds__(256, 2) void fused_kernel(
    const float* __restrict__ x,
    const _Float16* __restrict__ rph, const _Float16* __restrict__ rpl,
    const _Float16* __restrict__ ph, const _Float16* __restrict__ pl,
    int* __restrict__ out) {
    __shared__ _Float16 Ah[64 * PAD_ROW];
    __shared__ _Float16 Al[64 * PAD_ROW];
    __shared__ float    P[64 * PPITCH];
    __shared__ float    ls[4][32];
    __shared__ int      li[4][32];

    const int tid  = threadIdx.x;
    const int lane = tid & 63;
    const int w    = tid >> 6;
    const int quad = lane >> 4, col = lane & 15;
    const int qb   = blockIdx.x * 64;

    // ======================= Phase 1: projection =======================
    const int srow = tid >> 3;        // 0..31
    const int skc  = (tid & 7) * 4;   // 0,4,..,28

    f32x4 acc[4][2];
#pragma unroll
    for (int mt = 0; mt < 4; ++mt)
#pragma unroll
        for (int h = 0; h < 2; ++h) acc[mt][h] = (f32x4){0.f, 0.f, 0.f, 0.f};

    float4 pre[2];
#pragma unroll
    for (int i = 0; i < 2; ++i)
        pre[i] = *(const float4*)&x[(size_t)(qb + srow + 32 * i) * D_IN + skc];

    for (int kb = 0; kb < 32; ++kb) {
#pragma unroll
        for (int i = 0; i < 2; ++i) {
            const float vv[4] = {pre[i].x, pre[i].y, pre[i].z, pre[i].w};
            f16x4 h4, l4;
#pragma unroll
            for (int j = 0; j < 4; ++j) {
                const float v = vv[j] * 512.0f;
                const _Float16 hv = (_Float16)v;
                h4[j] = hv;
                l4[j] = (_Float16)(v - (float)hv);
            }
            const int base = (srow + 32 * i) * PAD_ROW + skc;
            *(f16x4*)&Ah[base] = h4;
            *(f16x4*)&Al[base] = l4;
        }
        __syncthreads();

        if (kb + 1 < 32) {
#pragma unroll
            for (int i = 0; i < 2; ++i)
                pre[i] = *(const float4*)&x[(size_t)(qb + srow + 32 * i) * D_IN + (kb + 1) * 32 + skc];
        }

        f16x8 bh1[2], bl1[2];
#pragma unroll
        for (int h = 0; h < 2; ++h) {
            const int nt = w * 2 + h;
            const size_t off = ((size_t)(kb * 8 + nt) * 64 + lane) * 8;
            bh1[h] = *(const f16x8*)&rph[off];
            bl1[h] = *(const f16x8*)&rpl[off];
        }

        f16x8 ah1[4], al1[4];
#pragma unroll
        for (int mt = 0; mt < 4; ++mt) {
            const int base = (mt * 16 + col) * PAD_ROW + quad * 8;
            ah1[mt] = *(const f16x8*)&Ah[base];
            al1[mt] = *(const f16x8*)&Al[base];
        }

#pragma unroll
        for (int mt = 0; mt < 4; ++mt)
#pragma unroll
            for (int h = 0; h < 2; ++h)
                acc[mt][h] = __builtin_amdgcn_mfma_f32_16x16x32_f16(ah1[mt], bh1[h], acc[mt][h], 0, 0, 0);
#pragma unroll
        for (int mt = 0; mt < 4; ++mt)
#pragma unroll
            for (int h = 0; h < 2; ++h)
                acc[mt][h] = __builtin_amdgcn_mfma_f32_16x16x32_f16(ah1[mt], bl1[h], acc[mt][h], 0, 0, 0);
#pragma unroll
        for (int mt = 0; mt < 4; ++mt)
#pragma unroll
            for (int h = 0; h < 2; ++h)
                acc[mt][h] = __builtin_amdgcn_mfma_f32_16x16x32_f16(al1[mt], bh1[h], acc[mt][h], 0, 0, 0);

        __syncthreads();
    }

    // Write proj*16 (f32) to LDS transpose buffer [query][k].
    // C/D: row(query) = mt*16 + quad*4 + r, col(k) = w*32 + h*16 + (lane&15).
#pragma unroll
    for (int mt = 0; mt < 4; ++mt)
#pragma unroll
        for (int h = 0; h < 2; ++h)
#pragma unroll
            for (int r = 0; r < 4; ++r) {
                const int row = mt * 16 + quad * 4 + r;
                const int cc  = w * 32 + h * 16 + col;
                P[row * PPITCH + cc] = acc[mt][h][r] * (1.0f / 2048.0f);
            }
    __syncthreads();

    // ======================= Phase 2: scores + argmax =======================
    const int wq = w >> 1;   // query half: m-tiles wq*2, wq*2+1
    const int wc = w & 1;    // code half: tiles [wc*256, wc*256+256)

    // A frags from LDS: A[m=col][k=quad*8+j], split hi/lo.
    f16x8 ah[2][4], al[2][4];
#pragma unroll
    for (int mt2 = 0; mt2 < 2; ++mt2)
#pragma unroll
        for (int kb = 0; kb < 4; ++kb) {
            const int base = (wq * 32 + mt2 * 16 + col) * PPITCH + kb * 32 + quad * 8;
            const float4 v0 = *(const float4*)&P[base];
            const float4 v1 = *(const float4*)&P[base + 4];
            const float vv[8] = {v0.x, v0.y, v0.z, v0.w, v1.x, v1.y, v1.z, v1.w};
            f16x8 hh, ll;
#pragma unroll
            for (int j = 0; j < 8; ++j) {
                const _Float16 hv = (_Float16)vv[j];
                hh[j] = hv;
                ll[j] = (_Float16)(vv[j] - (float)hv);
            }
            ah[mt2][kb] = hh;
            al[mt2][kb] = ll;
        }

    float bs[8];
    int   bi[8];
#pragma unroll
    for (int s = 0; s < 8; ++s) { bs[s] = -FLT_MAX; bi[s] = 0; }

    const int g0 = wc * 256;

    // B double buffer in registers.
    f16x8 bh[2][4], bl[2][4];
#pragma unroll
    for (int kb = 0; kb < 4; ++kb) {
        const size_t off = ((size_t)(g0 * 4 + kb) * 64 + lane) * 8;
        bh[0][kb] = *(const f16x8*)&ph[off];
        bl[0][kb] = *(const f16x8*)&pl[off];
    }

#pragma unroll 2
    for (int t = 0; t < 256; ++t) {
        const int cur = t & 1, nxt = cur ^ 1;
        if (t + 1 < 256) {
            const int gn = g0 + t + 1;
#pragma unroll
            for (int kb = 0; kb < 4; ++kb) {
                const size_t off = ((size_t)(gn * 4 + kb) * 64 + lane) * 8;
                bh[nxt][kb] = *(const f16x8*)&ph[off];
                bl[nxt][kb] = *(const f16x8*)&pl[off];
            }
        }

        f32x4 sacc[2];
#pragma unroll
        for (int mt2 = 0; mt2 < 2; ++mt2) sacc[mt2] = (f32x4){0.f, 0.f, 0.f, 0.f};

#pragma unroll
        for (int kb = 0; kb < 4; ++kb)
#pragma unroll
            for (int mt2 = 0; mt2 < 2; ++mt2)
                sacc[mt2] = __builtin_amdgcn_mfma_f32_16x16x32_f16(ah[mt2][kb], bh[cur][kb], sacc[mt2], 0, 0, 0);
#pragma unroll
        for (int kb = 0; kb < 4; ++kb)
#pragma unroll
            for (int mt2 = 0; mt2 < 2; ++mt2)
                sacc[mt2] = __builtin_amdgcn_mfma_f32_16x16x32_f16(ah[mt2][kb], bl[cur][kb], sacc[mt2], 0, 0, 0);
#pragma unroll
        for (int kb = 0; kb < 4; ++kb)
#pragma unroll
            for (int mt2 = 0; mt2 < 2; ++mt2)
                sacc[mt2] = __builtin_amdgcn_mfma_f32_16x16x32_f16(al[mt2][kb], bh[cur][kb], sacc[mt2], 0, 0, 0);

        const int code = (g0 + t) * 16 + col;
#pragma unroll
        for (int mt2 = 0; mt2 < 2; ++mt2)
#pragma unroll
            for (int r = 0; r < 4; ++r) {
                const float v = sacc[mt2][r];
                const int s = mt2 * 4 + r;
                if (v > bs[s]) { bs[s] = v; bi[s] = code; }  // ascending codes: > keeps min idx
            }
    }

    // Reduce the 16 code-columns per query (lanes differ in low 4 bits).
#pragma unroll
    for (int s = 0; s < 8; ++s) {
#pragma unroll
        for (int m = 1; m < 16; m <<= 1) {
            const float os = __shfl_xor(bs[s], m);
            const int   oi = __shfl_xor(bi[s], m);
            if (os > bs[s] || (os == bs[s] && oi < bi[s])) { bs[s] = os; bi[s] = oi; }
        }
    }

    if (col == 0) {
#pragma unroll
        for (int mt2 = 0; mt2 < 2; ++mt2)
#pragma unroll
            for (int r = 0; r < 4; ++r) {
                ls[w][mt2 * 16 + quad * 4 + r] = bs[mt2 * 4 + r];
                li[w][mt2 * 16 + quad * 4 + r] = bi[mt2 * 4 + r];
            }
    }
    __syncthreads();

    // Merge the two code halves (wc=0 codes < wc=1 codes: strict > keeps min idx).
    if (tid < 64) {
        const int q   = tid;
        const int wq2 = q >> 5;
        const int q32 = q & 31;
        float s = ls[wq2 * 2 + 0][q32];
        int   i = li[wq2 * 2 + 0][q32];
        const float os = ls[wq2 * 2 + 1][q32];
        if (os > s) { s = os; i = li[wq2 * 2 + 1][q32]; }
        out[qb + q] = i;
    }
}

// ---------------------------------------------------------------------------
extern "C" void kernel_launch(void* const* d_in, const int* in_sizes, int n_in,
                              void* d_out, int out_size, void* d_ws, size_t ws_size,
                              hipStream_t stream) {
    const float* x  = (const float*)d_in[0];   // [8,4096,1024]
    const float* rp = (const float*)d_in[1];   // [1024,128]
    const float* cb = (const float*)d_in[2];   // [8192,128]
    int* out = (int*)d_out;                    // [8,4096] int32

    _Float16* ph  = (_Float16*)d_ws;                         // 2 MB
    _Float16* pl  = ph  + (size_t)CB_N * E_DIM;              // 2 MB
    _Float16* rph = pl  + (size_t)CB_N * E_DIM;              // 256 KB
    _Float16* rpl = rph + (size_t)D_IN * E_DIM;              // 256 KB

    pack_cb_kernel<<<CB_N / 16, 256, 0, stream>>>(cb, ph, pl);
    pack_rp_kernel<<<256, 64, 0, stream>>>(rp, rph, rpl);
    fused_kernel<<<BN / 64, 256, 0, stream>>>(x, rph, rpl, ph, pl, out);
}